// Round 15
// baseline (52.561 us; speedup 1.0000x reference)
//
#include <hip/hip_runtime.h>

// Sliding-window attention, window=127 (+-63), B=4 L=4096 NH=16 H=64, fp32 in/out.
// Round-15: 3 independent barrier groups per CU (the last coherent lever).
// Evidence: dur tracks neither occupancy (19-55% -> 49-65us) nor traffic; all
// monolithic 2-blocks/CU configs sit at 49-54us; waves added INSIDE a barrier group
// (R12) don't help -> independent blocks are the latency-hiding streams.
//  - CQ=64: block = 64 queries, window 192 rows = 6 tiles. K [192][64]f16 24KB +
//    V^T [64][384B] 24KB = 48KB -> 3 blocks/CU (3 streams vs 2).
//  - 4096 blocks x 256 thr; 4 waves = 2 q-tiles x 2-way key-split (part0 3 tiles,
//    part1 2 tiles); R9 O^T orientation; part1 publishes partial O+denom into dead
//    K-region LDS, part0 combines (lane-local dinv) + direct float4 stores.
//  - Q direct strided loads (R11/R13/R14-proven correct; ~+15MB unsaturated fetch).
//  - FROZEN RULE (R3/R5): no register prefetch pinned across MFMA, no sched_barrier.

typedef _Float16 f16;
typedef _Float16 f16x2  __attribute__((ext_vector_type(2)));
typedef _Float16 f16x4  __attribute__((ext_vector_type(4)));
typedef _Float16 f16x8  __attribute__((ext_vector_type(8)));
typedef float    f32x16 __attribute__((ext_vector_type(16)));
typedef int      int4v  __attribute__((ext_vector_type(4)));

constexpr int NB = 4, L = 4096, NH = 16, H = 64;
constexpr int CQ = 64, NC = L / CQ, KW = 192, WR = 63;
constexpr int NBLK = NB * NH * NC;   // 4096
constexpr int RS = NH * H;           // seq-row stride in floats

constexpr int K_OFF = 0;         // [192][64] f16 rows (128B, swizzled) = 24 KB
constexpr int V_OFF = 24576;     // [64][384B] transposed (swizzled) = 24 KB
constexpr int X_OFF = 0;         // exchange [64h][64q] f32 = 16 KB (aliases dead K)
constexpr int D_OFF = 16384;     // partial denom [64] f32 (in dead K region)
constexpr int LDS_BYTES = 49152; // 48 KiB -> 3 blocks/CU

#define DEV static __device__ __forceinline__

DEV int iclamp(int x, int lo, int hi) { return x < lo ? lo : (x > hi ? hi : x); }

DEV float fexp2(float x) {
#if __has_builtin(__builtin_amdgcn_exp2f)
    return __builtin_amdgcn_exp2f(x);
#else
    return exp2f(x);
#endif
}

DEV int packh2(float a, float b) {
    f16x2 p; p.x = (f16)a; p.y = (f16)b;   // RNE casts
    return __builtin_bit_cast(int, p);
}

// K: row r (0..191), byte col (0..127), swizzled (bits 4..6 flip, stays in 128B row)
DEV int kaddr(int r, int colb) {
    return K_OFF + r * 128 + (colb ^ ((r & 7) << 4));
}

// V: (row h 0..63, key byte kb 0..383), swizzle flips bits 4..6 within 128B segment
DEV int vaddr(int h, int kb) {
    return V_OFF + ((h * 384 + kb) ^ ((((h & 7) ^ ((h >> 3) & 7))) << 4));
}

// After call: a = [a_lo | b_lo], b = [a_hi | b_hi]. HW-verified (R7+).
DEV void swap_halves(int& a, int& b) {
    asm volatile("v_permlane32_swap_b32 %0, %1" : "+v"(a), "+v"(b));
}

__global__ __launch_bounds__(256, 3)
void wattn_kernel(const float* __restrict__ q_, const float* __restrict__ k_,
                  const float* __restrict__ v_, float* __restrict__ o_)
{
    __shared__ alignas(16) char smem[LDS_BYTES];
    float* X_lds = (float*)(smem + X_OFF);   // post-compute alias
    float* D_lds = (float*)(smem + D_OFF);

    // XCD-aware swizzle: 4096 blocks, 8 XCDs, 4096%8==0 -> bijective;
    // consecutive chunks of one (b,n) land on one XCD -> window overlap L2 hits.
    const int bid = (int)blockIdx.x;
    const int wid = (bid & 7) * (NBLK / 8) + (bid >> 3);
    const int c = wid & (NC - 1);
    const int n = (wid >> 6) & (NH - 1);
    const int b = wid >> 10;

    const int t    = (int)threadIdx.x;
    const int lane = t & 63;
    const int w    = t >> 6;        // wave 0..3
    const int lq   = lane & 31;
    const int hi   = lane >> 5;
    const int qt   = w & 1;         // query tile 0..1 (32 rows)
    const int part = w >> 1;        // 0: tiles qt..qt+2, 1: qt+3..qt+4

    const int kg0 = c * CQ - WR;                       // global seq row of window key j=0
    const size_t bn = ((size_t)b * L * NH + n) * H;    // element offset of (b,0,n,0)
    const float qs = 0.125f * 1.44269504088896f;       // h^-0.5 * log2(e)

    // staging thread->element mapping: 16 threads per 256B source row
    const int h4 = (t & 15) << 2;    // float col 0,4,..,60
    const int cb = h4 << 1;          // f16 byte col
    const int ru = t >> 4;           // 0..15

    // ---- Q prologue: direct strided loads -> scaled f16 fragments ----
    const int iq = qt * 32 + lq;
    const float* qrow = q_ + bn + (size_t)(c * CQ + iq) * RS + hi * 8;
    f16x8 qf[4];
    #pragma unroll
    for (int tq = 0; tq < 4; ++tq) {
        float4 a  = *(const float4*)(qrow + tq * 16);
        float4 b2 = *(const float4*)(qrow + tq * 16 + 4);
        qf[tq] = (f16x8){(f16)(a.x * qs),  (f16)(a.y * qs),  (f16)(a.z * qs),  (f16)(a.w * qs),
                         (f16)(b2.x * qs), (f16)(b2.y * qs), (f16)(b2.z * qs), (f16)(b2.w * qs)};
    }

    // ---- K stage: rows 0..191 (edge-clamped; masked in softmax) ----
    #pragma unroll
    for (int p = 0; p < 12; ++p) {
        int r  = ru + p * 16;
        int kr = iclamp(kg0 + r, 0, L - 1);
        float4 x = *(const float4*)(k_ + bn + (size_t)kr * RS + h4);
        *(f16x4*)(smem + kaddr(r, cb)) = (f16x4){(f16)x.x, (f16)x.y, (f16)x.z, (f16)x.w};
    }
    // ---- V stage: transposed [64h][192k], dual-row ----
    #pragma unroll
    for (int p = 0; p < 6; ++p) {
        int r0  = ru * 2 + p * 32;
        int kr0 = iclamp(kg0 + r0,     0, L - 1);
        int kr1 = iclamp(kg0 + r0 + 1, 0, L - 1);
        float4 v0 = *(const float4*)(v_ + bn + (size_t)kr0 * RS + h4);
        float4 v1 = *(const float4*)(v_ + bn + (size_t)kr1 * RS + h4);
        int kb = r0 * 2;
        *(f16x2*)(smem + vaddr(h4 + 0, kb)) = (f16x2){(f16)v0.x, (f16)v1.x};
        *(f16x2*)(smem + vaddr(h4 + 1, kb)) = (f16x2){(f16)v0.y, (f16)v1.y};
        *(f16x2*)(smem + vaddr(h4 + 2, kb)) = (f16x2){(f16)v0.z, (f16)v1.z};
        *(f16x2*)(smem + vaddr(h4 + 3, kb)) = (f16x2){(f16)v0.w, (f16)v1.w};
    }

    // window mask bounds: allowed local keys j with j-iq in [0,126] and kg0+j in [0,L)
    const int jlo = (c == 0) ? WR : 0;
    const int jhi = (KW < L - kg0) ? KW : (L - kg0);
    const int lo  = (iq > jlo) ? iq : jlo;
    const int hb  = (iq + 126 < jhi - 1) ? (iq + 126) : (jhi - 1);
    const unsigned span = (unsigned)(hb - lo);

    f32x16 o0, o1;   // O^T fragments: lane holds row q=iq, h = (r&3)+8(r>>2)+4hi (+32 for o1)
    #pragma unroll
    for (int r = 0; r < 16; ++r) { o0[r] = 0.f; o1[r] = 0.f; }
    float dsum = 0.f;

    __syncthreads();   // b0: staging complete

    auto body = [&](int tl) {
        // K fragments (A-operand: lane holds K[k=tl*32+lq][h=16tq+8hi+j])
        f16x8 kf[4];
        #pragma unroll
        for (int tq = 0; tq < 4; ++tq)
            kf[tq] = *(const f16x8*)(smem + kaddr(tl * 32 + lq, 32 * tq + 16 * hi));

        // S^T tile
        f32x16 s;
        #pragma unroll
        for (int r = 0; r < 16; ++r) s[r] = 0.f;
        #pragma unroll
        for (int tq = 0; tq < 4; ++tq)
            s = __builtin_amdgcn_mfma_f32_32x32x16_f16(kf[tq], qf[tq], s, 0, 0, 0);

        // mask + exp2 + denominator (per-lane: q = iq)
        const int jb = tl * 32 + 4 * hi;
        float pe[16];
        #pragma unroll
        for (int r = 0; r < 16; ++r) {
            int j = jb + (r & 3) + ((r >> 2) << 3);      // D-row -> local key index
            float e = fexp2(s[r]);
            e = ((unsigned)(j - lo) <= span) ? e : 0.f;
            dsum += e;
            pe[r] = e;
        }
        int d0 = packh2(pe[0],  pe[1]),  d1 = packh2(pe[2],  pe[3]);
        int d2 = packh2(pe[4],  pe[5]),  d3 = packh2(pe[6],  pe[7]);
        int d4 = packh2(pe[8],  pe[9]),  d5 = packh2(pe[10], pe[11]);
        int d6 = packh2(pe[12], pe[13]), d7 = packh2(pe[14], pe[15]);
        swap_halves(d0, d2); swap_halves(d1, d3);
        swap_halves(d4, d6); swap_halves(d5, d7);
        f16x8 pa0 = __builtin_bit_cast(f16x8, (int4v){d0, d1, d2, d3});   // keys tl*32 + 0..15
        f16x8 pa1 = __builtin_bit_cast(f16x8, (int4v){d4, d5, d6, d7});   // keys tl*32 + 16..31

        // PV flipped: O^T[h][q] += V^T . P  (vb as A, pa as B)
        const int kb = tl * 64 + hi * 16;
        f16x8 vb00 = *(const f16x8*)(smem + vaddr(lq,      kb));
        f16x8 vb01 = *(const f16x8*)(smem + vaddr(lq,      kb + 32));
        f16x8 vb10 = *(const f16x8*)(smem + vaddr(32 + lq, kb));
        f16x8 vb11 = *(const f16x8*)(smem + vaddr(32 + lq, kb + 32));
        o0 = __builtin_amdgcn_mfma_f32_32x32x16_f16(vb00, pa0, o0, 0, 0, 0);
        o0 = __builtin_amdgcn_mfma_f32_32x32x16_f16(vb01, pa1, o0, 0, 0, 0);
        o1 = __builtin_amdgcn_mfma_f32_32x32x16_f16(vb10, pa0, o1, 0, 0, 0);
        o1 = __builtin_amdgcn_mfma_f32_32x32x16_f16(vb11, pa1, o1, 0, 0, 0);
    };

    // key-split: part0 tiles qt..qt+2, part1 tiles qt+3..qt+4
    const int kt0 = qt + part * 3;
    body(kt0);
    body(kt0 + 1);
    if (!part) body(kt0 + 2);

    // per-query partial denominator (q = iq lane-local in O^T orientation)
    float dw = dsum + __shfl_xor(dsum, 32, 64);

    __syncthreads();   // b1: all K/V LDS reads done; K region dead -> exchange buffers

    if (part) {
        // part 1 (2 tiles): publish unnormalized partial O^T and partial denom
        #pragma unroll
        for (int r = 0; r < 16; ++r) {
            int h = (r & 3) + ((r >> 2) << 3) + 4 * hi;
            X_lds[h * 64 + iq]        = o0[r];
            X_lds[(32 + h) * 64 + iq] = o1[r];
        }
        if (lane < 32) D_lds[iq] = dw;
    }
    __syncthreads();   // b2: partials visible

    if (!part) {
        // part 0 (3 tiles): combine, normalize (dinv lane-local), direct float4 stores
        float dinv = 1.0f / (dw + D_lds[iq]);
        const size_t ob = ((size_t)b * L + (size_t)c * CQ) * RS + (size_t)n * H;
        float* orow = o_ + ob + (size_t)iq * RS;
        #pragma unroll
        for (int m = 0; m < 4; ++m) {
            int h0 = 8 * m + 4 * hi;
            float4 v0, v1;
            v0.x = (o0[4 * m + 0] + X_lds[(h0 + 0) * 64 + iq]) * dinv;
            v0.y = (o0[4 * m + 1] + X_lds[(h0 + 1) * 64 + iq]) * dinv;
            v0.z = (o0[4 * m + 2] + X_lds[(h0 + 2) * 64 + iq]) * dinv;
            v0.w = (o0[4 * m + 3] + X_lds[(h0 + 3) * 64 + iq]) * dinv;
            v1.x = (o1[4 * m + 0] + X_lds[(32 + h0 + 0) * 64 + iq]) * dinv;
            v1.y = (o1[4 * m + 1] + X_lds[(32 + h0 + 1) * 64 + iq]) * dinv;
            v1.z = (o1[4 * m + 2] + X_lds[(32 + h0 + 2) * 64 + iq]) * dinv;
            v1.w = (o1[4 * m + 3] + X_lds[(32 + h0 + 3) * 64 + iq]) * dinv;
            *(float4*)(orow + h0)      = v0;
            *(float4*)(orow + 32 + h0) = v1;
        }
    }
}

extern "C" void kernel_launch(void* const* d_in, const int* in_sizes, int n_in,
                              void* d_out, int out_size, void* d_ws, size_t ws_size,
                              hipStream_t stream) {
    const float* q = (const float*)d_in[0];
    const float* k = (const float*)d_in[1];
    const float* v = (const float*)d_in[2];
    float* o = (float*)d_out;
    (void)in_sizes; (void)n_in; (void)out_size; (void)d_ws; (void)ws_size;
    wattn_kernel<<<dim3(NBLK), dim3(256), 0, stream>>>(q, k, v, o);
}

// Round 16
// 49.115 us; speedup vs baseline: 1.0702x; 1.0702x over previous
//
#include <hip/hip_runtime.h>

// Sliding-window attention, window=127 (+-63), B=4 L=4096 NH=16 H=64, fp32 in/out.
// FINAL (= Round-10, measured best 49.1us): monolithic stage -> barrier -> compute,
// 512 threads, key-split wave pairs, O^T-flipped PV epilogue.
// Convergence evidence (R1-R15): occupancy 19->55% null; ILP/setprio/prefetch null or
// spill-pathological; traffic cuts (CQ=256, persistent ring) increased FETCH or dur;
// 3-stream blocks null. Plateau 49-55us with all pipes <30% utilized -> per-block
// serial phase-latency floor for this decomposition.
//  - Q,K,V staged once per block to LDS as f16 (swizzled layouts, conflicts ~2.1M);
//    K/V via coalesced float4; epilogue uses lane-local dinv + direct float4 stores
//    (32B-granule write-combining verified clean: WRITE_SIZE = 65.5MB exact).
//  - permlane32_swap for P-fragment half exchange (HW-verified).
//  - FROZEN RULE (R3+R5): no register prefetch pinned across MFMA, no sched_barrier.

typedef _Float16 f16;
typedef _Float16 f16x2  __attribute__((ext_vector_type(2)));
typedef _Float16 f16x4  __attribute__((ext_vector_type(4)));
typedef _Float16 f16x8  __attribute__((ext_vector_type(8)));
typedef float    f32x16 __attribute__((ext_vector_type(16)));
typedef int      int4v  __attribute__((ext_vector_type(4)));

constexpr int NB = 4, L = 4096, NH = 16, H = 64;
constexpr int CQ = 128, NC = L / CQ, KW = 256, WR = 63;
constexpr int RS = NH * H;   // seq-row stride in floats

constexpr int Q_OFF = 0;         // [128][64] f16, 128B rows, swizzled (16 KB)
constexpr int K_OFF = 16384;     // [256][64] f16, 128B rows, swizzled (32 KB)
constexpr int V_OFF = 49152;     // [64][256] f16 transposed, 512B rows, swizzled (32 KB)
constexpr int LDS_BYTES = 81920; // 80 KiB -> exactly 2 blocks/CU

#define DEV static __device__ __forceinline__

DEV int iclamp(int x, int lo, int hi) { return x < lo ? lo : (x > hi ? hi : x); }

DEV float fexp2(float x) {
#if __has_builtin(__builtin_amdgcn_exp2f)
    return __builtin_amdgcn_exp2f(x);
#else
    return exp2f(x);
#endif
}

DEV int packh2(float a, float b) {
    f16x2 p; p.x = (f16)a; p.y = (f16)b;   // RNE casts
    return __builtin_bit_cast(int, p);
}

// byte offset in row-major [R][64] f16 tile (128B rows), bank-conflict swizzle
DEV int rmaddr(int base, int r, int colb) {
    return base + r * 128 + (colb ^ ((r & 7) << 4));
}

// byte offset of (row h, key byte kb) in transposed V_lds (512B rows)
DEV int vaddr(int h, int kb) {
    return V_OFF + ((h * 512 + kb) ^ ((((h & 7) ^ ((h >> 3) & 7))) << 4));
}

// After call: a = [a_lo | b_lo], b = [a_hi | b_hi]. HW-verified in R7.
DEV void swap_halves(int& a, int& b) {
    asm volatile("v_permlane32_swap_b32 %0, %1" : "+v"(a), "+v"(b));
}

__global__ __launch_bounds__(512) __attribute__((amdgpu_waves_per_eu(2, 4)))
void wattn_kernel(const float* __restrict__ q_, const float* __restrict__ k_,
                  const float* __restrict__ v_, float* __restrict__ o_)
{
    __shared__ alignas(16) char smem[LDS_BYTES];
    float* O_lds = (float*)smem;              // [64][128] fp32 partials, aliases Q+K post-b1
    float* D_lds = (float*)(smem + 32768);    // 128 partial denominators (in old K region)

    // XCD-aware swizzle: 2048 blocks, 8 XCDs, 2048%8==0 -> bijective
    const int bid = (int)blockIdx.x;
    const int wid = (bid & 7) * ((NB * NH * NC) / 8) + (bid >> 3);
    const int c = wid & (NC - 1);
    const int n = (wid >> 5) & (NH - 1);
    const int b = wid >> 9;

    const int t    = (int)threadIdx.x;
    const int lane = t & 63;
    const int w    = t >> 6;        // wave 0..7
    const int lq   = lane & 31;
    const int hi   = lane >> 5;
    const int qt   = w & 3;         // query tile 0..3
    const int half = w >> 2;        // 0: key tiles qt..qt+2, 1: qt+3..qt+4

    const int kg0 = c * CQ - WR;                       // global seq row of window key j=0
    const size_t bn = ((size_t)b * L * NH + n) * H;    // element offset of (b,0,n,0)
    const float qs = 0.125f * 1.44269504088896f;       // h^-0.5 * log2(e)

    // staging thread->element mapping: 32 threads per 256B source row region
    const int h4 = (t & 15) << 2;    // float col 0,4,..,60
    const int cb = h4 << 1;          // f16 byte col
    const int ru = t >> 4;           // 0..31

    // ================= staging: LOAD ALL =================
    float4 kb_[8], qb_[4], vb_[8];
    {
        #pragma unroll
        for (int p = 0; p < 8; ++p) {
            int kr = iclamp(kg0 + ru + p * 32, 0, L - 1);
            kb_[p] = *(const float4*)(k_ + bn + (size_t)kr * RS + h4);
        }
        const float* qp = q_ + bn + (size_t)(c * CQ) * RS + h4;
        #pragma unroll
        for (int p = 0; p < 4; ++p)
            qb_[p] = *(const float4*)(qp + (size_t)(ru + p * 32) * RS);
        #pragma unroll
        for (int p = 0; p < 4; ++p) {
            int r0  = ru * 2 + p * 64;
            vb_[2 * p]     = *(const float4*)(v_ + bn + (size_t)iclamp(kg0 + r0,     0, L - 1) * RS + h4);
            vb_[2 * p + 1] = *(const float4*)(v_ + bn + (size_t)iclamp(kg0 + r0 + 1, 0, L - 1) * RS + h4);
        }
    }
    // ================= staging: WRITE ALL (cvt + ds_write) =================
    #pragma unroll
    for (int p = 0; p < 8; ++p) {
        float4 x = kb_[p];
        *(f16x4*)(smem + rmaddr(K_OFF, ru + p * 32, cb)) =
            (f16x4){(f16)x.x, (f16)x.y, (f16)x.z, (f16)x.w};
    }
    #pragma unroll
    for (int p = 0; p < 4; ++p) {
        float4 x = qb_[p];
        *(f16x4*)(smem + rmaddr(Q_OFF, ru + p * 32, cb)) =
            (f16x4){(f16)(x.x * qs), (f16)(x.y * qs), (f16)(x.z * qs), (f16)(x.w * qs)};
    }
    #pragma unroll
    for (int p = 0; p < 4; ++p) {
        float4 v0 = vb_[2 * p], v1 = vb_[2 * p + 1];
        int kb = (ru * 2 + p * 64) * 2;
        *(f16x2*)(smem + vaddr(h4 + 0, kb)) = (f16x2){(f16)v0.x, (f16)v1.x};
        *(f16x2*)(smem + vaddr(h4 + 1, kb)) = (f16x2){(f16)v0.y, (f16)v1.y};
        *(f16x2*)(smem + vaddr(h4 + 2, kb)) = (f16x2){(f16)v0.z, (f16)v1.z};
        *(f16x2*)(smem + vaddr(h4 + 3, kb)) = (f16x2){(f16)v0.w, (f16)v1.w};
    }

    // window mask bounds: allowed local keys j with j-iq in [0,126] and kg0+j in [0,L)
    const int iq  = qt * 32 + lq;
    const int jlo = (c == 0) ? WR : 0;
    const int jhi = (KW < L - kg0) ? KW : (L - kg0);
    const int lo  = (iq > jlo) ? iq : jlo;
    const int hb  = (iq + 126 < jhi - 1) ? (iq + 126) : (jhi - 1);
    const unsigned span = (unsigned)(hb - lo);

    f32x16 o0, o1;   // O^T fragments: lane holds row q=lq, h chunks (r&3)+8(r>>2)+4hi (+32 for o1)
    #pragma unroll
    for (int r = 0; r < 16; ++r) { o0[r] = 0.f; o1[r] = 0.f; }
    float dsum = 0.f;

    __syncthreads();   // staging complete

    // ---- Q fragments from LDS (B-operand: lane holds Q[q=lq][h=16tq+8hi+j]) ----
    f16x8 qf[4];
    #pragma unroll
    for (int tq = 0; tq < 4; ++tq)
        qf[tq] = *(const f16x8*)(smem + rmaddr(Q_OFF, qt * 32 + lq, 32 * tq + 16 * hi));

    auto body = [&](int kt) {
        // K fragments (A-operand: lane holds K[k=kt*32+lq][h=16tq+8hi+j])
        f16x8 kf[4];
        #pragma unroll
        for (int tq = 0; tq < 4; ++tq)
            kf[tq] = *(const f16x8*)(smem + rmaddr(K_OFF, kt * 32 + lq, 32 * tq + 16 * hi));

        // S^T tile = K_tile(32k x 64h) . Q^T
        f32x16 s;
        #pragma unroll
        for (int r = 0; r < 16; ++r) s[r] = 0.f;
        #pragma unroll
        for (int tq = 0; tq < 4; ++tq)
            s = __builtin_amdgcn_mfma_f32_32x32x16_f16(kf[tq], qf[tq], s, 0, 0, 0);

        // mask + exp2 + denominator (per-lane: q = lq)
        const int jb = kt * 32 + 4 * hi;
        float pe[16];
        #pragma unroll
        for (int r = 0; r < 16; ++r) {
            int j = jb + (r & 3) + ((r >> 2) << 3);      // D-row -> local key index
            float e = fexp2(s[r]);
            e = ((unsigned)(j - lo) <= span) ? e : 0.f;
            dsum += e;
            pe[r] = e;
        }
        // P fragments: pack to f16 pairs, exchange across lane halves
        int d0 = packh2(pe[0],  pe[1]),  d1 = packh2(pe[2],  pe[3]);
        int d2 = packh2(pe[4],  pe[5]),  d3 = packh2(pe[6],  pe[7]);
        int d4 = packh2(pe[8],  pe[9]),  d5 = packh2(pe[10], pe[11]);
        int d6 = packh2(pe[12], pe[13]), d7 = packh2(pe[14], pe[15]);
        swap_halves(d0, d2); swap_halves(d1, d3);
        swap_halves(d4, d6); swap_halves(d5, d7);
        f16x8 pa0 = __builtin_bit_cast(f16x8, (int4v){d0, d1, d2, d3});   // keys kt*32 + 0..15
        f16x8 pa1 = __builtin_bit_cast(f16x8, (int4v){d4, d5, d6, d7});   // keys kt*32 + 16..31

        // PV flipped: O^T[h][q] += V^T . P  (vb as A, pa as B)
        const int kb = kt * 64 + hi * 16;
        f16x8 vb00 = *(const f16x8*)(smem + vaddr(lq,      kb));
        f16x8 vb01 = *(const f16x8*)(smem + vaddr(lq,      kb + 32));
        f16x8 vb10 = *(const f16x8*)(smem + vaddr(32 + lq, kb));
        f16x8 vb11 = *(const f16x8*)(smem + vaddr(32 + lq, kb + 32));
        o0 = __builtin_amdgcn_mfma_f32_32x32x16_f16(vb00, pa0, o0, 0, 0, 0);
        o0 = __builtin_amdgcn_mfma_f32_32x32x16_f16(vb01, pa1, o0, 0, 0, 0);
        o1 = __builtin_amdgcn_mfma_f32_32x32x16_f16(vb10, pa0, o1, 0, 0, 0);
        o1 = __builtin_amdgcn_mfma_f32_32x32x16_f16(vb11, pa1, o1, 0, 0, 0);
    };

    // key-split: low wave tiles qt..qt+2, high wave qt+3..qt+4
    const int kt0 = qt + half * 3;
    body(kt0);
    body(kt0 + 1);
    if (!half) body(kt0 + 2);

    // per-query partial denominator (q = lq is lane-local in this orientation)
    float dw = dsum + __shfl_xor(dsum, 32, 64);

    __syncthreads();   // b1: all waves done reading Q/K/V LDS; reuse for partials

    if (!half) {
        // LOW wave (3 tiles): publish unnormalized partial O^T and partial denom.
        #pragma unroll
        for (int r = 0; r < 16; ++r) {
            int h = (r & 3) + ((r >> 2) << 3) + 4 * hi;
            O_lds[h * 128 + iq]        = o0[r];
            O_lds[(32 + h) * 128 + iq] = o1[r];
        }
        if (lane < 32) D_lds[iq] = dw;
    }
    __syncthreads();   // b2

    if (half) {
        // HIGH wave (2 tiles): combine, normalize (dinv lane-local), direct float4 stores.
        float dinv = 1.0f / (dw + D_lds[iq]);
        const size_t ob = ((size_t)b * L + (size_t)c * CQ) * RS + (size_t)n * H;
        float* orow = o_ + ob + (size_t)iq * RS;
        #pragma unroll
        for (int m = 0; m < 4; ++m) {
            int h0 = 8 * m + 4 * hi;
            float4 v0, v1;
            v0.x = (o0[4 * m + 0] + O_lds[(h0 + 0) * 128 + iq]) * dinv;
            v0.y = (o0[4 * m + 1] + O_lds[(h0 + 1) * 128 + iq]) * dinv;
            v0.z = (o0[4 * m + 2] + O_lds[(h0 + 2) * 128 + iq]) * dinv;
            v0.w = (o0[4 * m + 3] + O_lds[(h0 + 3) * 128 + iq]) * dinv;
            v1.x = (o1[4 * m + 0] + O_lds[(32 + h0 + 0) * 128 + iq]) * dinv;
            v1.y = (o1[4 * m + 1] + O_lds[(32 + h0 + 1) * 128 + iq]) * dinv;
            v1.z = (o1[4 * m + 2] + O_lds[(32 + h0 + 2) * 128 + iq]) * dinv;
            v1.w = (o1[4 * m + 3] + O_lds[(32 + h0 + 3) * 128 + iq]) * dinv;
            *(float4*)(orow + h0)      = v0;
            *(float4*)(orow + 32 + h0) = v1;
        }
    }
}

extern "C" void kernel_launch(void* const* d_in, const int* in_sizes, int n_in,
                              void* d_out, int out_size, void* d_ws, size_t ws_size,
                              hipStream_t stream) {
    const float* q = (const float*)d_in[0];
    const float* k = (const float*)d_in[1];
    const float* v = (const float*)d_in[2];
    float* o = (float*)d_out;
    (void)in_sizes; (void)n_in; (void)out_size; (void)d_ws; (void)ws_size;
    wattn_kernel<<<dim3(NB * NH * NC), dim3(512), 0, stream>>>(q, k, v, o);
}